// Round 2
// baseline (1758.529 us; speedup 1.0000x reference)
//
#include <hip/hip_runtime.h>
#include <math.h>

// MMD with Gaussian kernel, bandwidth=512, X:[N,512] Y:[M,512] fp32.
// out = (S_XX - n)/(n(n-1)) - 2*S_XY/(nm) + (S_YY - m)/(m(m-1))
// where S_AB = sum_{i,j} exp(-||a_i - b_j||^2 / 512).
//
// Fused GEMM+exp+reduce on fp32 vector ALU (no fp32 MFMA on CDNA4), f64
// accumulation (output needs ~7e-8 rel accuracy on ~9.1e6 sums due to the
// xx-2xy+yy cancellation).
//
// CRITICAL: the harness 'np' reference follows the fp32 jax path:
//   lse = m + log(sum(exp(-d2/512 - m))) in fp32, then exp(lse) in fp32.
// Rounding lse to fp32 (ulp(16)=1.9e-6) perturbs each S by up to ~17 units
// — 100x our own numerical error, and 2.6% of the cancelled output. So we
// compute S near-exactly in f64, then EMULATE the reference's fp32
// logsumexp->exp->combine bit-for-bit (m from min d2; correctly-rounded
// f32 log/exp via f64 libm; fp32 combine in source order).

#define D   512
#define BM  128
#define BN  128
#define BK  16
#define LDA (BM + 4)   // pad: transpose stores land 2 lanes/bank (free)

__global__ __launch_bounds__(256)
void row_norms_kernel(const float* __restrict__ X, const float* __restrict__ Y,
                      float* __restrict__ X2, float* __restrict__ Y2, int N, int M) {
    const int wave = threadIdx.x >> 6;
    const int lane = threadIdx.x & 63;
    const int row  = blockIdx.x * 4 + wave;      // one wave64 per row
    const float* src; float* dst; int r;
    if (row < N)          { src = X; dst = X2; r = row; }
    else if (row < N + M) { src = Y; dst = Y2; r = row - N; }
    else return;
    const float* p = src + (size_t)r * D;
    float s = 0.f;
    #pragma unroll
    for (int c = 0; c < D; c += 64) {            // coalesced
        float v = p[c + lane];
        s = fmaf(v, v, s);
    }
    #pragma unroll
    for (int off = 32; off > 0; off >>= 1) s += __shfl_down(s, off);
    if (lane == 0) dst[r] = s;
}

// order-preserving map: ascending uint key order == ascending float order
__device__ inline unsigned float_key(float f) {
    unsigned u = __float_as_uint(f);
    return (u & 0x80000000u) ? ~u : (u | 0x80000000u);
}
__device__ inline float key_float(unsigned k) {
    return __uint_as_float((k & 0x80000000u) ? (k ^ 0x80000000u) : ~k);
}

// grid (N/BM, M/BN, 3): z=0 -> XX (symmetric), z=1 -> XY, z=2 -> YY (symmetric)
__global__ __launch_bounds__(256, 2)
void pair_exp_sum_kernel(const float* __restrict__ X, const float* __restrict__ Y,
                         const float* __restrict__ X2, const float* __restrict__ Y2,
                         double* __restrict__ accum, unsigned* __restrict__ minkey) {
    const int z = blockIdx.z;
    const float *A, *B, *An, *Bn;
    bool sym;
    if (z == 0)      { A = X; B = X; An = X2; Bn = X2; sym = true;  }
    else if (z == 1) { A = X; B = Y; An = X2; Bn = Y2; sym = false; }
    else             { A = Y; B = Y; An = Y2; Bn = Y2; sym = true;  }

    const int bi = blockIdx.x, bj = blockIdx.y;
    if (sym && bj < bi) return;                  // triangular skip (weight 2 below)

    __shared__ float As[BK][LDA];                // As[k][m] = A[row0+m][k0+k]
    __shared__ float Bs[BK][LDA];

    const int tid = threadIdx.x;
    const int tx  = tid & 15;                    // n-dim
    const int ty  = tid >> 4;                    // m-dim

    const int row0 = bi * BM;
    const int col0 = bj * BN;

    const int lr0 = tid >> 2;                    // 0..63
    const int lc0 = (tid & 3) * 4;               // k-offset 0/4/8/12

    const float* Ar0 = A + (size_t)(row0 + lr0)      * D + lc0;
    const float* Ar1 = A + (size_t)(row0 + lr0 + 64) * D + lc0;
    const float* Br0 = B + (size_t)(col0 + lr0)      * D + lc0;
    const float* Br1 = B + (size_t)(col0 + lr0 + 64) * D + lc0;

    float acc[8][8];
    #pragma unroll
    for (int i = 0; i < 8; i++)
        #pragma unroll
        for (int j = 0; j < 8; j++) acc[i][j] = 0.f;

    for (int k0 = 0; k0 < D; k0 += BK) {
        float4 a0 = *(const float4*)(Ar0 + k0);
        float4 a1 = *(const float4*)(Ar1 + k0);
        float4 b0 = *(const float4*)(Br0 + k0);
        float4 b1 = *(const float4*)(Br1 + k0);
        __syncthreads();                         // prev-iter LDS reads done
        As[lc0+0][lr0]    = a0.x; As[lc0+1][lr0]    = a0.y; As[lc0+2][lr0]    = a0.z; As[lc0+3][lr0]    = a0.w;
        As[lc0+0][lr0+64] = a1.x; As[lc0+1][lr0+64] = a1.y; As[lc0+2][lr0+64] = a1.z; As[lc0+3][lr0+64] = a1.w;
        Bs[lc0+0][lr0]    = b0.x; Bs[lc0+1][lr0]    = b0.y; Bs[lc0+2][lr0]    = b0.z; Bs[lc0+3][lr0]    = b0.w;
        Bs[lc0+0][lr0+64] = b1.x; Bs[lc0+1][lr0+64] = b1.y; Bs[lc0+2][lr0+64] = b1.z; Bs[lc0+3][lr0+64] = b1.w;
        __syncthreads();
        #pragma unroll
        for (int k = 0; k < BK; k++) {
            float a[8], b[8];
            *(float4*)&a[0] = *(const float4*)&As[k][ty * 4];        // 4+4 split:
            *(float4*)&a[4] = *(const float4*)&As[k][ty * 4 + 64];   // broadcast / 2-way = free
            *(float4*)&b[0] = *(const float4*)&Bs[k][tx * 4];
            *(float4*)&b[4] = *(const float4*)&Bs[k][tx * 4 + 64];
            #pragma unroll
            for (int i = 0; i < 8; i++)
                #pragma unroll
                for (int j = 0; j < 8; j++)
                    acc[i][j] = fmaf(a[i], b[j], acc[i][j]);
        }
    }

    // epilogue: d2 = |a|^2 + |b|^2 - 2 a.b ; w = exp(-d2/512); sum + min(d2)
    int mr[8], nc[8];
    #pragma unroll
    for (int q = 0; q < 4; q++) {
        mr[q] = row0 + ty * 4 + q;  mr[q + 4] = mr[q] + 64;
        nc[q] = col0 + tx * 4 + q;  nc[q + 4] = nc[q] + 64;
    }
    float an[8], bn[8];
    #pragma unroll
    for (int i = 0; i < 8; i++) { an[i] = An[mr[i]]; bn[i] = Bn[nc[i]]; }

    double s = 0.0;
    float dmin = 1e30f;
    #pragma unroll
    for (int i = 0; i < 8; i++) {
        float rs = 0.f;
        #pragma unroll
        for (int j = 0; j < 8; j++) {
            float d2 = an[i] + bn[j] - 2.0f * acc[i][j];
            dmin = fminf(dmin, d2);
            rs += expf(d2 * (-1.0f / 512.0f));   // ocml expf
        }
        s += (double)rs;                         // fp32 only over 8 terms, then f64
    }

    // block reduce: f64 sum + f32 min -> one atomic each per block
    #pragma unroll
    for (int off = 32; off > 0; off >>= 1) {
        s += __shfl_down(s, off);
        dmin = fminf(dmin, __shfl_down(dmin, off));
    }
    __shared__ double wsum[4];
    __shared__ float  wmin[4];
    const int wave = tid >> 6, lane = tid & 63;
    if (lane == 0) { wsum[wave] = s; wmin[wave] = dmin; }
    __syncthreads();
    if (tid == 0) {
        double tot = wsum[0] + wsum[1] + wsum[2] + wsum[3];
        if (sym && bj > bi) tot *= 2.0;          // off-diagonal counted twice
        atomicAdd(&accum[z], tot);               // global_atomic_add_f64
        float bm = fminf(fminf(wmin[0], wmin[1]), fminf(wmin[2], wmin[3]));
        atomicMin(&minkey[z], float_key(bm));
    }
}

__global__ void finalize_kernel(const double* __restrict__ accum,
                                const unsigned* __restrict__ minkey,
                                float* __restrict__ out, int N, int M) {
    if (threadIdx.x == 0 && blockIdx.x == 0) {
        float Sp[3];
        #pragma unroll
        for (int z = 0; z < 3; z++) {
            // emulate fp32 jax.nn.logsumexp + jnp.exp:
            //   m = max(-d2/512)  (exact: /512 is an exponent shift)
            float m = key_float(minkey[z]) * (-1.0f / 512.0f);
            double Sshift = accum[z] * exp(-(double)m);   // == sum(exp(x - m)), near-exact
            float r = (float)log(Sshift);                 // correctly-rounded f32 log
            float lse = r + m;                            // fp32 add, as jax does
            Sp[z] = (float)exp((double)lse);              // correctly-rounded f32 exp
        }
        // fp32 combine in reference source order
        float nf  = (float)N, mf = (float)M;
        float nn1 = (float)((double)N * (double)(N - 1));   // 67100672, exact in fp32
        float mm1 = (float)((double)M * (double)(M - 1));
        float nm  = (float)((double)N * (double)M);         // 2^26, exact
        float xx = (Sp[0] - nf) / nn1;
        float xy =  Sp[1]       / nm;
        float yy = (Sp[2] - mf) / mm1;
        out[0] = xx - 2.0f * xy + yy;
    }
}

extern "C" void kernel_launch(void* const* d_in, const int* in_sizes, int n_in,
                              void* d_out, int out_size, void* d_ws, size_t ws_size,
                              hipStream_t stream) {
    const float* X = (const float*)d_in[0];
    const float* Y = (const float*)d_in[1];
    const int N = in_sizes[0] / D;
    const int M = in_sizes[1] / D;

    // ws layout: [0,24) 3 f64 accumulators; [32,44) 3 u32 min-keys; [64,..) X2[N], Y2[M]
    double*   accum  = (double*)d_ws;
    unsigned* minkey = (unsigned*)((char*)d_ws + 32);
    float*    X2     = (float*)((char*)d_ws + 64);
    float*    Y2     = X2 + N;

    hipMemsetAsync(accum, 0, 32, stream);          // zero f64 accumulators
    hipMemsetAsync(minkey, 0xFF, 32, stream);      // min-keys = UINT_MAX

    const int rows = N + M;
    row_norms_kernel<<<(rows + 3) / 4, 256, 0, stream>>>(X, Y, X2, Y2, N, M);

    dim3 grid(N / BM, M / BN, 3);                  // N==M==8192 here
    pair_exp_sum_kernel<<<grid, 256, 0, stream>>>(X, Y, X2, Y2, accum, minkey);

    finalize_kernel<<<1, 64, 0, stream>>>(accum, minkey, (float*)d_out, N, M);
}

// Round 3
// 691.413 us; speedup vs baseline: 2.5434x; 2.5434x over previous
//
#include <hip/hip_runtime.h>
#include <math.h>

// MMD, Gaussian kernel, bandwidth=512. X:[8192,512] Y:[8192,512] fp32.
// S_AB = sum_ij exp(-||a_i-b_j||^2/512); combine emulating the reference's
// fp32 logsumexp->exp->combine path (see finalize_kernel).
//
// Round-3 change: GEMM on the 2.5 PF bf16 matrix pipe via split-bf16
// 3-product: x = hi + lo (RNE bf16; x-hi Sterbenz-exact), dot = hi*hi' +
// hi*lo' + lo*hi' in fp32-accumulating MFMA. d2 error ~1.2e-4 == same scale
// as np reference's own fp32 GEMM noise (round-2 relationship preserved).
// fp32 VALU path measured 78.8 TF (50% of its 157 TF roofline); this moves
// the inner product to v_mfma_f32_32x32x16_bf16.

#define D   512
#define BT  128
#define BK  16

typedef __attribute__((ext_vector_type(8)))  short  short8;   // 8 bf16 = 4 VGPR
typedef __attribute__((ext_vector_type(16))) float  f32x16;   // 32x32 acc

__device__ __forceinline__ unsigned short bf16_rne(float x) {
    unsigned u = __float_as_uint(x);
    return (unsigned short)((u + 0x7fffu + ((u >> 16) & 1u)) >> 16);
}
__device__ __forceinline__ float bf16_f32(unsigned short b) {
    return __uint_as_float(((unsigned)b) << 16);
}
// x -> (hi, lo) bf16 pairs, packed 8-wide into uint4s
__device__ __forceinline__ void split8(const float v[8], uint4& hi, uint4& lo) {
    unsigned h[8], l[8];
    #pragma unroll
    for (int j = 0; j < 8; j++) {
        unsigned short bh = bf16_rne(v[j]);
        float r = v[j] - bf16_f32(bh);          // exact (Sterbenz)
        unsigned short bl = bf16_rne(r);
        h[j] = bh; l[j] = bl;
    }
    hi.x = h[0] | (h[1] << 16); hi.y = h[2] | (h[3] << 16);
    hi.z = h[4] | (h[5] << 16); hi.w = h[6] | (h[7] << 16);
    lo.x = l[0] | (l[1] << 16); lo.y = l[2] | (l[3] << 16);
    lo.z = l[4] | (l[5] << 16); lo.w = l[6] | (l[7] << 16);
}

__global__ __launch_bounds__(256)
void row_norms_kernel(const float* __restrict__ X, const float* __restrict__ Y,
                      float* __restrict__ X2, float* __restrict__ Y2, int N, int M) {
    const int wave = threadIdx.x >> 6;
    const int lane = threadIdx.x & 63;
    const int row  = blockIdx.x * 4 + wave;
    const float* src; float* dst; int r;
    if (row < N)          { src = X; dst = X2; r = row; }
    else if (row < N + M) { src = Y; dst = Y2; r = row - N; }
    else return;
    const float* p = src + (size_t)r * D;
    float s = 0.f;
    #pragma unroll
    for (int c = 0; c < D; c += 64) {
        float v = p[c + lane];
        s = fmaf(v, v, s);
    }
    #pragma unroll
    for (int off = 32; off > 0; off >>= 1) s += __shfl_down(s, off);
    if (lane == 0) dst[r] = s;
}

// order-preserving float<->uint key (for atomicMin over f32)
__device__ inline unsigned float_key(float f) {
    unsigned u = __float_as_uint(f);
    return (u & 0x80000000u) ? ~u : (u | 0x80000000u);
}
__device__ inline float key_float(unsigned k) {
    return __uint_as_float((k & 0x80000000u) ? (k ^ 0x80000000u) : ~k);
}

// grid (64,64,3): z=0 XX (sym), z=1 XY, z=2 YY (sym)
__global__ __launch_bounds__(256, 3)
void pair_exp_sum_kernel(const float* __restrict__ X, const float* __restrict__ Y,
                         const float* __restrict__ X2, const float* __restrict__ Y2,
                         double* __restrict__ accum, unsigned* __restrict__ minkey) {
    const int z = blockIdx.z;
    const float *A, *B, *An, *Bn; bool sym;
    if (z == 0)      { A = X; B = X; An = X2; Bn = X2; sym = true;  }
    else if (z == 1) { A = X; B = Y; An = X2; Bn = Y2; sym = false; }
    else             { A = Y; B = Y; An = Y2; Bn = Y2; sym = true;  }
    const int bi = blockIdx.x, bj = blockIdx.y;
    if (sym && bj < bi) return;                  // triangular skip (weight 2 below)

    // LDS: [buf][Ahi,Alo,Bhi,Blo][point*2 + khalf] in 16B units (8 bf16)
    // writes: thread t -> unit t (contiguous, conflict-free)
    // frag reads: dword 8*(lane&31)+4*(lane>>5): each bank hit 8x distinct = min cycles
    __shared__ uint4  smem[2][4][BT * BK / 8];
    __shared__ float  smN[2 * BT];
    __shared__ double wsum[4];
    __shared__ float  wmin[4];

    const int tid  = threadIdx.x;
    const int wave = tid >> 6, lane = tid & 63;
    const int wy = wave >> 1, wx = wave & 1;     // 2x2 waves, each 64x64
    const int row0 = bi * BT, col0 = bj * BT;

    // block norms -> LDS (rows then cols)
    if (tid < BT) smN[tid] = An[row0 + tid];
    else          smN[tid] = Bn[col0 + (tid - BT)];

    // staging: thread t owns point p=t>>1, k-half h=t&1 (8 fp32 -> hi/lo bf16)
    const int sp = tid >> 1, sh = tid & 1;
    const float* gA = A + (size_t)(row0 + sp) * D + sh * 8;
    const float* gB = B + (size_t)(col0 + sp) * D + sh * 8;
    const int su = sp * 2 + sh;

    // MFMA A/B frag source: lane -> point (lane&31) in group, k-half (lane>>5)
    const int fp = lane & 31, fh = lane >> 5;
    const int au0 = (64 * wy + fp) * 2 + fh, au1 = au0 + 64;   // +32 points
    const int bu0 = (64 * wx + fp) * 2 + fh, bu1 = bu0 + 64;

    f32x16 acc00, acc01, acc10, acc11;
    #pragma unroll
    for (int i = 0; i < 16; i++) { acc00[i] = 0.f; acc01[i] = 0.f; acc10[i] = 0.f; acc11[i] = 0.f; }

    auto stage = [&](int buf, const float4& a0, const float4& a1,
                     const float4& b0, const float4& b1) {
        float va[8] = {a0.x, a0.y, a0.z, a0.w, a1.x, a1.y, a1.z, a1.w};
        uint4 hi, lo;
        split8(va, hi, lo);
        smem[buf][0][su] = hi; smem[buf][1][su] = lo;
        float vb[8] = {b0.x, b0.y, b0.z, b0.w, b1.x, b1.y, b1.z, b1.w};
        split8(vb, hi, lo);
        smem[buf][2][su] = hi; smem[buf][3][su] = lo;
    };

    auto compute = [&](int buf) {
        const short8* pAhi = (const short8*)smem[buf][0];
        const short8* pAlo = (const short8*)smem[buf][1];
        const short8* pBhi = (const short8*)smem[buf][2];
        const short8* pBlo = (const short8*)smem[buf][3];
        short8 ah0 = pAhi[au0], ah1 = pAhi[au1];
        short8 al0 = pAlo[au0], al1 = pAlo[au1];
        short8 bh0 = pBhi[bu0], bh1 = pBhi[bu1];
        short8 bl0 = pBlo[bu0], bl1 = pBlo[bu1];
        acc00 = __builtin_amdgcn_mfma_f32_32x32x16_bf16(ah0, bh0, acc00, 0, 0, 0);
        acc01 = __builtin_amdgcn_mfma_f32_32x32x16_bf16(ah0, bh1, acc01, 0, 0, 0);
        acc10 = __builtin_amdgcn_mfma_f32_32x32x16_bf16(ah1, bh0, acc10, 0, 0, 0);
        acc11 = __builtin_amdgcn_mfma_f32_32x32x16_bf16(ah1, bh1, acc11, 0, 0, 0);
        acc00 = __builtin_amdgcn_mfma_f32_32x32x16_bf16(ah0, bl0, acc00, 0, 0, 0);
        acc01 = __builtin_amdgcn_mfma_f32_32x32x16_bf16(ah0, bl1, acc01, 0, 0, 0);
        acc10 = __builtin_amdgcn_mfma_f32_32x32x16_bf16(ah1, bl0, acc10, 0, 0, 0);
        acc11 = __builtin_amdgcn_mfma_f32_32x32x16_bf16(ah1, bl1, acc11, 0, 0, 0);
        acc00 = __builtin_amdgcn_mfma_f32_32x32x16_bf16(al0, bh0, acc00, 0, 0, 0);
        acc01 = __builtin_amdgcn_mfma_f32_32x32x16_bf16(al0, bh1, acc01, 0, 0, 0);
        acc10 = __builtin_amdgcn_mfma_f32_32x32x16_bf16(al1, bh0, acc10, 0, 0, 0);
        acc11 = __builtin_amdgcn_mfma_f32_32x32x16_bf16(al1, bh1, acc11, 0, 0, 0);
    };

    // prologue: stage k0=0 into buf 0
    {
        float4 a0 = *(const float4*)(gA),     a1 = *(const float4*)(gA + 4);
        float4 b0 = *(const float4*)(gB),     b1 = *(const float4*)(gB + 4);
        stage(0, a0, a1, b0, b1);
    }
    __syncthreads();

    int pb = 0;
    for (int k0 = BK; k0 < D; k0 += BK) {
        float4 a0 = *(const float4*)(gA + k0),     a1 = *(const float4*)(gA + k0 + 4);
        float4 b0 = *(const float4*)(gB + k0),     b1 = *(const float4*)(gB + k0 + 4);
        compute(pb);                              // overlap: loads in flight
        stage(pb ^ 1, a0, a1, b0, b1);            // other buffer: no race with readers of pb
        __syncthreads();
        pb ^= 1;
    }
    compute(pb);

    // epilogue: d2 = |a|^2+|b|^2-2ab; track min d2; sum exp(-d2/512)
    // C/D layout (verified m74/m101): col=lane&31, row=(reg&3)+8*(reg>>2)+4*(lane>>5)
    double s = 0.0;
    float dmin = 1e30f;
    const float* rowN = &smN[64 * wy];
    const float* colN = &smN[BT + 64 * wx];
    auto tile_epi = [&](const f32x16& a, int gi, int gj) {
        float cn = colN[32 * gj + fp];
        float rs = 0.f;
        #pragma unroll
        for (int r = 0; r < 16; r++) {
            int r32 = (r & 3) + 8 * (r >> 2) + 4 * fh;
            float d2 = rowN[32 * gi + r32] + cn - 2.0f * a[r];
            dmin = fminf(dmin, d2);
            rs += expf(d2 * (-1.0f / 512.0f));    // fp32 chunk of 16, then f64
        }
        s += (double)rs;
    };
    tile_epi(acc00, 0, 0); tile_epi(acc01, 0, 1);
    tile_epi(acc10, 1, 0); tile_epi(acc11, 1, 1);

    #pragma unroll
    for (int off = 32; off > 0; off >>= 1) {
        s += __shfl_down(s, off);
        dmin = fminf(dmin, __shfl_down(dmin, off));
    }
    if (lane == 0) { wsum[wave] = s; wmin[wave] = dmin; }
    __syncthreads();
    if (tid == 0) {
        double tot = wsum[0] + wsum[1] + wsum[2] + wsum[3];
        if (sym && bj > bi) tot *= 2.0;           // mirrored block not computed
        atomicAdd(&accum[z], tot);                // device-scope f64 atomic
        float bm = fminf(fminf(wmin[0], wmin[1]), fminf(wmin[2], wmin[3]));
        atomicMin(&minkey[z], float_key(bm));
    }
}

__global__ void finalize_kernel(const double* __restrict__ accum,
                                const unsigned* __restrict__ minkey,
                                float* __restrict__ out, int N, int M) {
    if (threadIdx.x == 0 && blockIdx.x == 0) {
        float Sp[3];
        #pragma unroll
        for (int z = 0; z < 3; z++) {
            // emulate fp32 jax logsumexp: m = max(-d2/512) (exact exponent shift)
            float m = key_float(minkey[z]) * (-1.0f / 512.0f);
            double Sshift = accum[z] * exp(-(double)m);
            float r = (float)log(Sshift);         // correctly-rounded f32 log
            float lse = r + m;                    // fp32 add, as jax
            Sp[z] = (float)exp((double)lse);      // correctly-rounded f32 exp
        }
        float nf  = (float)N, mf = (float)M;
        float nn1 = (float)((double)N * (double)(N - 1));
        float mm1 = (float)((double)M * (double)(M - 1));
        float nm  = (float)((double)N * (double)M);
        float xx = (Sp[0] - nf) / nn1;
        float xy =  Sp[1]       / nm;
        float yy = (Sp[2] - mf) / mm1;
        out[0] = xx - 2.0f * xy + yy;
    }
}

extern "C" void kernel_launch(void* const* d_in, const int* in_sizes, int n_in,
                              void* d_out, int out_size, void* d_ws, size_t ws_size,
                              hipStream_t stream) {
    const float* X = (const float*)d_in[0];
    const float* Y = (const float*)d_in[1];
    const int N = in_sizes[0] / D;
    const int M = in_sizes[1] / D;

    double*   accum  = (double*)d_ws;
    unsigned* minkey = (unsigned*)((char*)d_ws + 32);
    float*    X2     = (float*)((char*)d_ws + 64);
    float*    Y2     = X2 + N;

    hipMemsetAsync(accum, 0, 32, stream);
    hipMemsetAsync(minkey, 0xFF, 32, stream);

    const int rows = N + M;
    row_norms_kernel<<<(rows + 3) / 4, 256, 0, stream>>>(X, Y, X2, Y2, N, M);

    dim3 grid(N / BT, M / BT, 3);
    pair_exp_sum_kernel<<<grid, 256, 0, stream>>>(X, Y, X2, Y2, accum, minkey);

    finalize_kernel<<<1, 64, 0, stream>>>(accum, minkey, (float*)d_out, N, M);
}

// Round 4
// 509.172 us; speedup vs baseline: 3.4537x; 1.3579x over previous
//
#include <hip/hip_runtime.h>
#include <math.h>

// MMD, Gaussian kernel, bandwidth=512. X:[8192,512] Y:[8192,512] fp32.
// S_AB = sum_ij exp(-||a_i-b_j||^2/512); final combine emulates the
// reference's fp32 logsumexp->exp->combine path (see finalize_kernel).
//
// GEMM on bf16 MFMA via split-bf16 3-product (hi*hi' + hi*lo' + lo*hi';
// x-hi is Sterbenz-exact). Round-4 change: the fp32->(hi,lo) split is
// hoisted into a one-time conversion pass (was 64x-redundant per-block,
// ~2x the MFMA cycles at VALUBusy=53%); pair kernel now stages bf16
// fragments from pre-swizzled global layout [kstep][point][16 bf16] via
// async global_load_lds width=16 (no VGPR round-trip, no VALU).
// d2 bits identical to the passing round-3 kernel.

#define D      512
#define BT     128
#define BK     16
#define KSTEPS (D / BK)

typedef __attribute__((ext_vector_type(8)))  short  short8;   // 8 bf16
typedef __attribute__((ext_vector_type(16))) float  f32x16;   // 32x32 acc

__device__ __forceinline__ unsigned short bf16_rne(float x) {
    unsigned u = __float_as_uint(x);
    return (unsigned short)((u + 0x7fffu + ((u >> 16) & 1u)) >> 16);
}
__device__ __forceinline__ float bf16_f32(unsigned short b) {
    return __uint_as_float(((unsigned)b) << 16);
}
__device__ __forceinline__ void split8(const float v[8], uint4& hi, uint4& lo) {
    unsigned h[8], l[8];
    #pragma unroll
    for (int j = 0; j < 8; j++) {
        unsigned short bh = bf16_rne(v[j]);
        float r = v[j] - bf16_f32(bh);          // exact (Sterbenz)
        unsigned short bl = bf16_rne(r);
        h[j] = bh; l[j] = bl;
    }
    hi.x = h[0] | (h[1] << 16); hi.y = h[2] | (h[3] << 16);
    hi.z = h[4] | (h[5] << 16); hi.w = h[6] | (h[7] << 16);
    lo.x = l[0] | (l[1] << 16); lo.y = l[2] | (l[3] << 16);
    lo.z = l[4] | (l[5] << 16); lo.w = l[6] | (l[7] << 16);
}

// async global->LDS, 16B per lane; LDS dest must be lane-contiguous
__device__ __forceinline__ void lds16(const uint4* g, uint4* l) {
    __builtin_amdgcn_global_load_lds(
        (const __attribute__((address_space(1))) void*)g,
        (__attribute__((address_space(3))) void*)(unsigned int)(uintptr_t)(void*)l,
        16, 0, 0);
}

// one-time split: src[npts][512] fp32 -> hi/lo as [kstep][point][16 bf16]
__global__ __launch_bounds__(256)
void convert_kernel(const float* __restrict__ src, uint4* __restrict__ hi,
                    uint4* __restrict__ lo, int npts) {
    const int ks = blockIdx.y;
    const int p  = blockIdx.x * 256 + threadIdx.x;
    if (p >= npts) return;
    const float* s = src + (size_t)p * D + ks * BK;
    float v[16];
    *(float4*)&v[0]  = *(const float4*)(s);
    *(float4*)&v[4]  = *(const float4*)(s + 4);
    *(float4*)&v[8]  = *(const float4*)(s + 8);
    *(float4*)&v[12] = *(const float4*)(s + 12);
    uint4 h0, l0, h1, l1;
    split8(&v[0], h0, l0);
    split8(&v[8], h1, l1);
    size_t u = ((size_t)ks * npts + p) * 2;     // uint4 units
    hi[u] = h0; hi[u + 1] = h1;
    lo[u] = l0; lo[u + 1] = l1;
}

__global__ __launch_bounds__(256)
void row_norms_kernel(const float* __restrict__ X, const float* __restrict__ Y,
                      float* __restrict__ X2, float* __restrict__ Y2, int N, int M) {
    const int wave = threadIdx.x >> 6;
    const int lane = threadIdx.x & 63;
    const int row  = blockIdx.x * 4 + wave;
    const float* src; float* dst; int r;
    if (row < N)          { src = X; dst = X2; r = row; }
    else if (row < N + M) { src = Y; dst = Y2; r = row - N; }
    else return;
    const float* p = src + (size_t)r * D;
    float s = 0.f;
    #pragma unroll
    for (int c = 0; c < D; c += 64) {
        float v = p[c + lane];
        s = fmaf(v, v, s);
    }
    #pragma unroll
    for (int off = 32; off > 0; off >>= 1) s += __shfl_down(s, off);
    if (lane == 0) dst[r] = s;
}

// order-preserving float<->uint key (for atomicMin over f32)
__device__ inline unsigned float_key(float f) {
    unsigned u = __float_as_uint(f);
    return (u & 0x80000000u) ? ~u : (u | 0x80000000u);
}
__device__ inline float key_float(unsigned k) {
    return __uint_as_float((k & 0x80000000u) ? (k ^ 0x80000000u) : ~k);
}

// grid (64,64,3): z=0 XX (sym), z=1 XY, z=2 YY (sym)
__global__ __launch_bounds__(256, 3)
void pair_exp_sum_kernel(const uint4* __restrict__ Xhi, const uint4* __restrict__ Xlo,
                         const uint4* __restrict__ Yhi, const uint4* __restrict__ Ylo,
                         const float* __restrict__ X2, const float* __restrict__ Y2,
                         double* __restrict__ accum, unsigned* __restrict__ minkey,
                         int N, int M) {
    const int z = blockIdx.z;
    const uint4 *Ahi, *Alo, *Bhi, *Blo; const float *An, *Bn; bool sym; int na, nb;
    if (z == 0)      { Ahi=Xhi; Alo=Xlo; Bhi=Xhi; Blo=Xlo; An=X2; Bn=X2; sym=true;  na=N; nb=N; }
    else if (z == 1) { Ahi=Xhi; Alo=Xlo; Bhi=Yhi; Blo=Ylo; An=X2; Bn=Y2; sym=false; na=N; nb=M; }
    else             { Ahi=Yhi; Alo=Ylo; Bhi=Yhi; Blo=Ylo; An=Y2; Bn=Y2; sym=true;  na=M; nb=M; }
    const int bi = blockIdx.x, bj = blockIdx.y;
    if (sym && bj < bi) return;                 // triangular skip (weight 2 below)

    // LDS: [buf][Ahi,Alo,Bhi,Blo][point*2 + khalf] in 16B units
    __shared__ uint4  smem[2][4][BT * BK / 8];
    __shared__ float  smN[2 * BT];
    __shared__ double wsum[4];
    __shared__ float  wmin[4];

    const int tid  = threadIdx.x;
    const int wave = tid >> 6, lane = tid & 63;
    const int wy = wave >> 1, wx = wave & 1;    // 2x2 waves, each 64x64
    const int row0 = bi * BT, col0 = bj * BT;

    if (tid < BT) smN[tid] = An[row0 + tid];
    else          smN[tid] = Bn[col0 + (tid - BT)];

    // staging: wave w stages units [w*64, w*64+64) of each array's 4KB slice
    const int wl = wave * 64 + lane;            // lane-contiguous LDS dest
    const size_t strideA = (size_t)na * 2;      // uint4 units per kstep
    const size_t strideB = (size_t)nb * 2;
    const uint4* gAhi = Ahi + (size_t)row0 * 2 + wl;
    const uint4* gAlo = Alo + (size_t)row0 * 2 + wl;
    const uint4* gBhi = Bhi + (size_t)col0 * 2 + wl;
    const uint4* gBlo = Blo + (size_t)col0 * 2 + wl;

    // MFMA frag indices: lane -> point (lane&31), k-half (lane>>5)
    const int fp = lane & 31, fh = lane >> 5;
    const int au0 = (64 * wy + fp) * 2 + fh, au1 = au0 + 64;
    const int bu0 = (64 * wx + fp) * 2 + fh, bu1 = bu0 + 64;

    f32x16 acc00, acc01, acc10, acc11;
    #pragma unroll
    for (int i = 0; i < 16; i++) { acc00[i] = 0.f; acc01[i] = 0.f; acc10[i] = 0.f; acc11[i] = 0.f; }

    auto stage = [&](int buf, int ks) {
        size_t ka = (size_t)ks * strideA, kb = (size_t)ks * strideB;
        lds16(gAhi + ka, &smem[buf][0][wl]);
        lds16(gAlo + ka, &smem[buf][1][wl]);
        lds16(gBhi + kb, &smem[buf][2][wl]);
        lds16(gBlo + kb, &smem[buf][3][wl]);
    };

    auto compute = [&](int buf) {
        const short8* pAhi = (const short8*)smem[buf][0];
        const short8* pAlo = (const short8*)smem[buf][1];
        const short8* pBhi = (const short8*)smem[buf][2];
        const short8* pBlo = (const short8*)smem[buf][3];
        short8 ah0 = pAhi[au0], ah1 = pAhi[au1];
        short8 al0 = pAlo[au0], al1 = pAlo[au1];
        short8 bh0 = pBhi[bu0], bh1 = pBhi[bu1];
        short8 bl0 = pBlo[bu0], bl1 = pBlo[bu1];
        acc00 = __builtin_amdgcn_mfma_f32_32x32x16_bf16(ah0, bh0, acc00, 0, 0, 0);
        acc01 = __builtin_amdgcn_mfma_f32_32x32x16_bf16(ah0, bh1, acc01, 0, 0, 0);
        acc10 = __builtin_amdgcn_mfma_f32_32x32x16_bf16(ah1, bh0, acc10, 0, 0, 0);
        acc11 = __builtin_amdgcn_mfma_f32_32x32x16_bf16(ah1, bh1, acc11, 0, 0, 0);
        acc00 = __builtin_amdgcn_mfma_f32_32x32x16_bf16(ah0, bl0, acc00, 0, 0, 0);
        acc01 = __builtin_amdgcn_mfma_f32_32x32x16_bf16(ah0, bl1, acc01, 0, 0, 0);
        acc10 = __builtin_amdgcn_mfma_f32_32x32x16_bf16(ah1, bl0, acc10, 0, 0, 0);
        acc11 = __builtin_amdgcn_mfma_f32_32x32x16_bf16(ah1, bl1, acc11, 0, 0, 0);
        acc00 = __builtin_amdgcn_mfma_f32_32x32x16_bf16(al0, bh0, acc00, 0, 0, 0);
        acc01 = __builtin_amdgcn_mfma_f32_32x32x16_bf16(al0, bh1, acc01, 0, 0, 0);
        acc10 = __builtin_amdgcn_mfma_f32_32x32x16_bf16(al1, bh0, acc10, 0, 0, 0);
        acc11 = __builtin_amdgcn_mfma_f32_32x32x16_bf16(al1, bh1, acc11, 0, 0, 0);
    };

    stage(0, 0);
    __syncthreads();                            // drains vmcnt (DMA) + lgkm

    int pb = 0;
    for (int ks = 1; ks < KSTEPS; ks++) {
        stage(pb ^ 1, ks);                      // async, overlaps compute(pb)
        compute(pb);
        __syncthreads();
        pb ^= 1;
    }
    compute(pb);

    // epilogue: d2 = |a|^2+|b|^2-2ab; track min d2; sum exp(-d2/512)
    // C/D layout (m74/m101): col=lane&31, row=(reg&3)+8*(reg>>2)+4*(lane>>5)
    double s = 0.0;
    float dmin = 1e30f;
    const float* rowN = &smN[64 * wy];
    const float* colN = &smN[BT + 64 * wx];
    auto tile_epi = [&](const f32x16& a, int gi, int gj) {
        float cn = colN[32 * gj + fp];
        float rs = 0.f;
        #pragma unroll
        for (int r = 0; r < 16; r++) {
            int r32 = (r & 3) + 8 * (r >> 2) + 4 * fh;
            float d2 = rowN[32 * gi + r32] + cn - 2.0f * a[r];
            dmin = fminf(dmin, d2);
            rs += expf(d2 * (-1.0f / 512.0f));
        }
        s += (double)rs;
    };
    tile_epi(acc00, 0, 0); tile_epi(acc01, 0, 1);
    tile_epi(acc10, 1, 0); tile_epi(acc11, 1, 1);

    #pragma unroll
    for (int off = 32; off > 0; off >>= 1) {
        s += __shfl_down(s, off);
        dmin = fminf(dmin, __shfl_down(dmin, off));
    }
    if (lane == 0) { wsum[wave] = s; wmin[wave] = dmin; }
    __syncthreads();
    if (tid == 0) {
        double tot = wsum[0] + wsum[1] + wsum[2] + wsum[3];
        if (sym && bj > bi) tot *= 2.0;
        atomicAdd(&accum[z], tot);
        float bm = fminf(fminf(wmin[0], wmin[1]), fminf(wmin[2], wmin[3]));
        atomicMin(&minkey[z], float_key(bm));
    }
}

__global__ void finalize_kernel(const double* __restrict__ accum,
                                const unsigned* __restrict__ minkey,
                                float* __restrict__ out, int N, int M) {
    if (threadIdx.x == 0 && blockIdx.x == 0) {
        float Sp[3];
        #pragma unroll
        for (int z = 0; z < 3; z++) {
            float m = key_float(minkey[z]) * (-1.0f / 512.0f);
            double Sshift = accum[z] * exp(-(double)m);
            float r = (float)log(Sshift);       // correctly-rounded f32 log
            float lse = r + m;                  // fp32 add, as jax
            Sp[z] = (float)exp((double)lse);    // correctly-rounded f32 exp
        }
        float nf  = (float)N, mf = (float)M;
        float nn1 = (float)((double)N * (double)(N - 1));
        float mm1 = (float)((double)M * (double)(M - 1));
        float nm  = (float)((double)N * (double)M);
        float xx = (Sp[0] - nf) / nn1;
        float xy =  Sp[1]       / nm;
        float yy = (Sp[2] - mf) / mm1;
        out[0] = xx - 2.0f * xy + yy;
    }
}

extern "C" void kernel_launch(void* const* d_in, const int* in_sizes, int n_in,
                              void* d_out, int out_size, void* d_ws, size_t ws_size,
                              hipStream_t stream) {
    const float* X = (const float*)d_in[0];
    const float* Y = (const float*)d_in[1];
    const int N = in_sizes[0] / D;
    const int M = in_sizes[1] / D;

    // ws: accum(3 f64)@0; minkey(3 u32)@32; X2@64; Y2; then 256B-aligned
    // swizzled bf16 arrays Xhi,Xlo,Yhi,Ylo (N*D*2 B each; 32 MB total)
    double*   accum  = (double*)d_ws;
    unsigned* minkey = (unsigned*)((char*)d_ws + 32);
    float*    X2     = (float*)((char*)d_ws + 64);
    float*    Y2     = X2 + N;
    size_t off = (64 + (size_t)(N + M) * 4 + 255) & ~(size_t)255;
    size_t asz = (size_t)N * D * 2;             // bytes per array (N==M)
    uint4* Xhi = (uint4*)((char*)d_ws + off);
    uint4* Xlo = (uint4*)((char*)d_ws + off + asz);
    uint4* Yhi = (uint4*)((char*)d_ws + off + 2 * asz);
    uint4* Ylo = (uint4*)((char*)d_ws + off + 3 * asz);

    hipMemsetAsync(accum, 0, 32, stream);
    hipMemsetAsync(minkey, 0xFF, 32, stream);

    row_norms_kernel<<<(N + M + 3) / 4, 256, 0, stream>>>(X, Y, X2, Y2, N, M);
    convert_kernel<<<dim3((N + 255) / 256, KSTEPS), 256, 0, stream>>>(X, Xhi, Xlo, N);
    convert_kernel<<<dim3((M + 255) / 256, KSTEPS), 256, 0, stream>>>(Y, Yhi, Ylo, M);

    dim3 grid(N / BT, M / BT, 3);
    pair_exp_sum_kernel<<<grid, 256, 0, stream>>>(Xhi, Xlo, Yhi, Ylo, X2, Y2,
                                                  accum, minkey, N, M);

    finalize_kernel<<<1, 64, 0, stream>>>(accum, minkey, (float*)d_out, N, M);
}

// Round 5
// 481.256 us; speedup vs baseline: 3.6540x; 1.0580x over previous
//
#include <hip/hip_runtime.h>
#include <math.h>

// MMD, Gaussian kernel, bandwidth=512. X:[8192,512] Y:[8192,512] fp32.
// S_AB = sum_ij exp(-||a_i-b_j||^2/512); final combine emulates the
// reference's fp32 logsumexp->exp->combine path (see finalize_kernel).
//
// GEMM on bf16 MFMA via split-bf16 3-product (hi*hi' + hi*lo' + lo*hi').
// Round-5: block tile 128x256, per-wave 64x128 (24 MFMA per wave per
// K-step). Round-4's 128x128 tile saturated the LDS port (reads 85 +
// DMA-writes 42 = 127 of 128 B/cyc at the MFMA floor); this tile needs
// only 94 B/cyc and doubles MFMA-per-barrier. d2 accumulation order is
// bit-identical to the passing round-3/4 kernels.

#define D      512
#define BTM    128
#define BTN    256
#define BK     16
#define KSTEPS (D / BK)

// LDS unit = uint4 = 16 B = 8 bf16 (half of one point's BK=16 k-row)
#define AHI 0
#define ALO 256
#define BHI 512
#define BLO 1024
#define UNITS 1536

typedef __attribute__((ext_vector_type(8)))  short  short8;   // 8 bf16
typedef __attribute__((ext_vector_type(16))) float  f32x16;   // 32x32 acc

__device__ __forceinline__ unsigned short bf16_rne(float x) {
    unsigned u = __float_as_uint(x);
    return (unsigned short)((u + 0x7fffu + ((u >> 16) & 1u)) >> 16);
}
__device__ __forceinline__ float bf16_f32(unsigned short b) {
    return __uint_as_float(((unsigned)b) << 16);
}
__device__ __forceinline__ void split8(const float v[8], uint4& hi, uint4& lo) {
    unsigned h[8], l[8];
    #pragma unroll
    for (int j = 0; j < 8; j++) {
        unsigned short bh = bf16_rne(v[j]);
        float r = v[j] - bf16_f32(bh);          // exact (Sterbenz)
        unsigned short bl = bf16_rne(r);
        h[j] = bh; l[j] = bl;
    }
    hi.x = h[0] | (h[1] << 16); hi.y = h[2] | (h[3] << 16);
    hi.z = h[4] | (h[5] << 16); hi.w = h[6] | (h[7] << 16);
    lo.x = l[0] | (l[1] << 16); lo.y = l[2] | (l[3] << 16);
    lo.z = l[4] | (l[5] << 16); lo.w = l[6] | (l[7] << 16);
}

// async global->LDS, 16B per lane; LDS dest lane-contiguous
__device__ __forceinline__ void lds16(const uint4* g, uint4* l) {
    __builtin_amdgcn_global_load_lds(
        (const __attribute__((address_space(1))) void*)g,
        (__attribute__((address_space(3))) void*)(unsigned int)(uintptr_t)(void*)l,
        16, 0, 0);
}

// one-time split: src[npts][512] fp32 -> hi/lo as [kstep][point][16 bf16]
__global__ __launch_bounds__(256)
void convert_kernel(const float* __restrict__ src, uint4* __restrict__ hi,
                    uint4* __restrict__ lo, int npts) {
    const int ks = blockIdx.y;
    const int p  = blockIdx.x * 256 + threadIdx.x;
    if (p >= npts) return;
    const float* s = src + (size_t)p * D + ks * BK;
    float v[16];
    *(float4*)&v[0]  = *(const float4*)(s);
    *(float4*)&v[4]  = *(const float4*)(s + 4);
    *(float4*)&v[8]  = *(const float4*)(s + 8);
    *(float4*)&v[12] = *(const float4*)(s + 12);
    uint4 h0, l0, h1, l1;
    split8(&v[0], h0, l0);
    split8(&v[8], h1, l1);
    size_t u = ((size_t)ks * npts + p) * 2;     // uint4 units
    hi[u] = h0; hi[u + 1] = h1;
    lo[u] = l0; lo[u + 1] = l1;
}

__global__ __launch_bounds__(256)
void row_norms_kernel(const float* __restrict__ X, const float* __restrict__ Y,
                      float* __restrict__ X2, float* __restrict__ Y2, int N, int M) {
    const int wave = threadIdx.x >> 6;
    const int lane = threadIdx.x & 63;
    const int row  = blockIdx.x * 4 + wave;
    const float* src; float* dst; int r;
    if (row < N)          { src = X; dst = X2; r = row; }
    else if (row < N + M) { src = Y; dst = Y2; r = row - N; }
    else return;
    const float* p = src + (size_t)r * D;
    float s = 0.f;
    #pragma unroll
    for (int c = 0; c < D; c += 64) {
        float v = p[c + lane];
        s = fmaf(v, v, s);
    }
    #pragma unroll
    for (int off = 32; off > 0; off >>= 1) s += __shfl_down(s, off);
    if (lane == 0) dst[r] = s;
}

// order-preserving float<->uint key (for atomicMin over f32)
__device__ inline unsigned float_key(float f) {
    unsigned u = __float_as_uint(f);
    return (u & 0x80000000u) ? ~u : (u | 0x80000000u);
}
__device__ inline float key_float(unsigned k) {
    return __uint_as_float((k & 0x80000000u) ? (k ^ 0x80000000u) : ~k);
}

// grid (64,32,3): z=0 XX (sym), z=1 XY, z=2 YY (sym)
__global__ __launch_bounds__(256, 2)
void pair_exp_sum_kernel(const uint4* __restrict__ Xhi, const uint4* __restrict__ Xlo,
                         const uint4* __restrict__ Yhi, const uint4* __restrict__ Ylo,
                         const float* __restrict__ X2, const float* __restrict__ Y2,
                         double* __restrict__ accum, unsigned* __restrict__ minkey,
                         int N, int M) {
    const int z = blockIdx.z;
    const uint4 *Ahi, *Alo, *Bhi, *Blo; const float *An, *Bn; bool sym; int na, nb;
    if (z == 0)      { Ahi=Xhi; Alo=Xlo; Bhi=Xhi; Blo=Xlo; An=X2; Bn=X2; sym=true;  na=N; nb=N; }
    else if (z == 1) { Ahi=Xhi; Alo=Xlo; Bhi=Yhi; Blo=Ylo; An=X2; Bn=Y2; sym=false; na=N; nb=M; }
    else             { Ahi=Yhi; Alo=Ylo; Bhi=Yhi; Blo=Ylo; An=Y2; Bn=Y2; sym=true;  na=M; nb=M; }
    const int bi = blockIdx.x, bj = blockIdx.y;
    if (sym && (2 * bj + 1) < bi) return;       // both 128-col halves below diag

    __shared__ uint4  smem[2][UNITS];           // 2 x 24 KB
    __shared__ float  smN[BTM + BTN];           // row norms (128) + col norms (256)
    __shared__ double wsum[4];
    __shared__ float  wmin[4];

    const int tid  = threadIdx.x;
    const int wave = tid >> 6, lane = tid & 63;
    const int wy = wave >> 1, wx = wave & 1;    // 2x2 waves, each 64x128
    const int row0 = bi * BTM, col0 = bj * BTN;

    if (tid < BTM) smN[tid] = An[row0 + tid];
    smN[BTM + tid] = Bn[col0 + tid];            // all 256 threads

    // staging bases (uint4 units); [kstep] stride = npts*2
    const int wl = wave * 64 + lane;            // lane-contiguous chunk id
    const size_t strideA = (size_t)na * 2;
    const size_t strideB = (size_t)nb * 2;
    const uint4* gAhi = Ahi + (size_t)row0 * 2 + wl;
    const uint4* gAlo = Alo + (size_t)row0 * 2 + wl;
    const uint4* gBhi = Bhi + (size_t)col0 * 2 + wl;
    const uint4* gBlo = Blo + (size_t)col0 * 2 + wl;

    // MFMA frag indices: lane -> point (lane&31), k-half (lane>>5)
    const int fp = lane & 31, fh = lane >> 5;
    int au[2], bu[4];
    #pragma unroll
    for (int g = 0; g < 2; g++) au[g] = (64 * wy + 32 * g + fp) * 2 + fh;
    #pragma unroll
    for (int c = 0; c < 4; c++) bu[c] = (128 * wx + 32 * c + fp) * 2 + fh;

    f32x16 acc[2][4];
    #pragma unroll
    for (int g = 0; g < 2; g++)
        #pragma unroll
        for (int c = 0; c < 4; c++)
            #pragma unroll
            for (int i = 0; i < 16; i++) acc[g][c][i] = 0.f;

    auto stage = [&](int buf, int ks) {
        size_t ka = (size_t)ks * strideA, kb = (size_t)ks * strideB;
        lds16(gAhi + ka,       &smem[buf][AHI + wl]);
        lds16(gAlo + ka,       &smem[buf][ALO + wl]);
        lds16(gBhi + kb,       &smem[buf][BHI + wl]);
        lds16(gBhi + kb + 256, &smem[buf][BHI + 256 + wl]);
        lds16(gBlo + kb,       &smem[buf][BLO + wl]);
        lds16(gBlo + kb + 256, &smem[buf][BLO + 256 + wl]);
    };

    auto compute = [&](int buf) {
        const short8* p = (const short8*)&smem[buf][0];
        short8 ah[2], al[2], bh[4], bl[4];
        #pragma unroll
        for (int g = 0; g < 2; g++) { ah[g] = p[AHI + au[g]]; al[g] = p[ALO + au[g]]; }
        #pragma unroll
        for (int c = 0; c < 4; c++) { bh[c] = p[BHI + bu[c]]; bl[c] = p[BLO + bu[c]]; }
        // same per-element order as round 3/4: all hh, all hl, all lh
        #pragma unroll
        for (int g = 0; g < 2; g++)
            #pragma unroll
            for (int c = 0; c < 4; c++)
                acc[g][c] = __builtin_amdgcn_mfma_f32_32x32x16_bf16(ah[g], bh[c], acc[g][c], 0, 0, 0);
        #pragma unroll
        for (int g = 0; g < 2; g++)
            #pragma unroll
            for (int c = 0; c < 4; c++)
                acc[g][c] = __builtin_amdgcn_mfma_f32_32x32x16_bf16(ah[g], bl[c], acc[g][c], 0, 0, 0);
        #pragma unroll
        for (int g = 0; g < 2; g++)
            #pragma unroll
            for (int c = 0; c < 4; c++)
                acc[g][c] = __builtin_amdgcn_mfma_f32_32x32x16_bf16(al[g], bh[c], acc[g][c], 0, 0, 0);
    };

    stage(0, 0);
    __syncthreads();                            // drains DMA + lgkm

    int pb = 0;
    for (int ks = 1; ks < KSTEPS; ks++) {
        stage(pb ^ 1, ks);                      // async, overlaps compute(pb)
        compute(pb);
        __syncthreads();
        pb ^= 1;
    }
    compute(pb);

    // per-wave triangular weight (col-128-half granularity)
    float wgt = 1.f;
    if (sym) {
        int cblk = 2 * bj + wx;                 // this wave's 128-col block id
        wgt = (cblk > bi) ? 2.f : (cblk == bi ? 1.f : 0.f);
    }

    // epilogue: d2 = |a|^2+|b|^2-2ab; min d2; sum exp(-d2/512)
    // C/D layout (m74/m101): col=lane&31, row=(reg&3)+8*(reg>>2)+4*(lane>>5)
    double s = 0.0;
    float dmin = 1e30f;
    if (wgt != 0.f) {
        const float* rowN = &smN[64 * wy];
        const float* colN = &smN[BTM + 128 * wx];
        #pragma unroll
        for (int g = 0; g < 2; g++)
            #pragma unroll
            for (int c = 0; c < 4; c++) {
                float cn = colN[32 * c + fp];
                float rs = 0.f;
                #pragma unroll
                for (int r = 0; r < 16; r++) {
                    int r32 = (r & 3) + 8 * (r >> 2) + 4 * fh;
                    float d2 = rowN[32 * g + r32] + cn - 2.0f * acc[g][c][r];
                    dmin = fminf(dmin, d2);
                    rs += expf(d2 * (-1.0f / 512.0f));
                }
                s += (double)rs;
            }
        s *= (double)wgt;
    }

    #pragma unroll
    for (int off = 32; off > 0; off >>= 1) {
        s += __shfl_down(s, off);
        dmin = fminf(dmin, __shfl_down(dmin, off));
    }
    if (lane == 0) { wsum[wave] = s; wmin[wave] = dmin; }
    __syncthreads();
    if (tid == 0) {
        double tot = wsum[0] + wsum[1] + wsum[2] + wsum[3];
        atomicAdd(&accum[z], tot);
        float bm = fminf(fminf(wmin[0], wmin[1]), fminf(wmin[2], wmin[3]));
        atomicMin(&minkey[z], float_key(bm));
    }
}

__global__ void finalize_kernel(const double* __restrict__ accum,
                                const unsigned* __restrict__ minkey,
                                float* __restrict__ out, int N, int M) {
    if (threadIdx.x == 0 && blockIdx.x == 0) {
        float Sp[3];
        #pragma unroll
        for (int z = 0; z < 3; z++) {
            float m = key_float(minkey[z]) * (-1.0f / 512.0f);
            double Sshift = accum[z] * exp(-(double)m);
            float r = (float)log(Sshift);       // correctly-rounded f32 log
            float lse = r + m;                  // fp32 add, as jax
            Sp[z] = (float)exp((double)lse);    // correctly-rounded f32 exp
        }
        float nf  = (float)N, mf = (float)M;
        float nn1 = (float)((double)N * (double)(N - 1));
        float mm1 = (float)((double)M * (double)(M - 1));
        float nm  = (float)((double)N * (double)M);
        float xx = (Sp[0] - nf) / nn1;
        float xy =  Sp[1]       / nm;
        float yy = (Sp[2] - mf) / mm1;
        out[0] = xx - 2.0f * xy + yy;
    }
}

extern "C" void kernel_launch(void* const* d_in, const int* in_sizes, int n_in,
                              void* d_out, int out_size, void* d_ws, size_t ws_size,
                              hipStream_t stream) {
    const float* X = (const float*)d_in[0];
    const float* Y = (const float*)d_in[1];
    const int N = in_sizes[0] / D;
    const int M = in_sizes[1] / D;

    // ws: accum(3 f64)@0; minkey(3 u32)@32; X2@64; Y2; then 256B-aligned
    // swizzled bf16 arrays Xhi,Xlo,Yhi,Ylo (N*D*2 B each; 32 MB total)
    double*   accum  = (double*)d_ws;
    unsigned* minkey = (unsigned*)((char*)d_ws + 32);
    float*    X2     = (float*)((char*)d_ws + 64);
    float*    Y2     = X2 + N;
    size_t off = (64 + (size_t)(N + M) * 4 + 255) & ~(size_t)255;
    size_t asz = (size_t)N * D * 2;             // bytes per array (N==M)
    uint4* Xhi = (uint4*)((char*)d_ws + off);
    uint4* Xlo = (uint4*)((char*)d_ws + off + asz);
    uint4* Yhi = (uint4*)((char*)d_ws + off + 2 * asz);
    uint4* Ylo = (uint4*)((char*)d_ws + off + 3 * asz);

    hipMemsetAsync(accum, 0, 32, stream);
    hipMemsetAsync(minkey, 0xFF, 32, stream);

    row_norms_kernel<<<(N + M + 3) / 4, 256, 0, stream>>>(X, Y, X2, Y2, N, M);
    convert_kernel<<<dim3((N + 255) / 256, KSTEPS), 256, 0, stream>>>(X, Xhi, Xlo, N);
    convert_kernel<<<dim3((M + 255) / 256, KSTEPS), 256, 0, stream>>>(Y, Yhi, Ylo, M);

    dim3 grid(N / BTM, M / BTN, 3);
    pair_exp_sum_kernel<<<grid, 256, 0, stream>>>(Xhi, Xlo, Yhi, Ylo, X2, Y2,
                                                  accum, minkey, N, M);

    finalize_kernel<<<1, 64, 0, stream>>>(accum, minkey, (float*)d_out, N, M);
}